// Round 16
// baseline (1311.864 us; speedup 1.0000x reference)
//
#include <hip/hip_runtime.h>

// ---------------------------------------------------------------------------
// GCN3D. R9: split-bf16 MFMA GEMMs. R10: proppool2. R12: NTW=4. R13: prop4s,
// norm-fold. R14: bf16 props. R15: pre-converted bf16 A for late GEMMs.
// R16: (a) k_gmfma 2-stage software pipeline (explicit ping-pong register
//   buffers prefetch k-step s+1's W/A before s's MFMAs -- compiler wasn't
//   hiding the ~200cyc L2 latency; VGPR 52->~120 is free headroom).
//   (b) h4 emits bf16 ONLY; instats/poolavg read bf16 Xh (saves ~200MB).
// ---------------------------------------------------------------------------

#define NCLUST 1024

typedef short bf16x8 __attribute__((ext_vector_type(8)));
typedef float f32x4 __attribute__((ext_vector_type(4)));

__device__ __forceinline__ float elu1(float x) { return x > 0.f ? x : expm1f(x); }

__device__ __forceinline__ unsigned f2bf(float f) {
    union { float f; unsigned u; } c; c.f = f;
    unsigned u = c.u;
    return (u + 0x7fffu + ((u >> 16) & 1u)) >> 16;
}
__device__ __forceinline__ float bf2f(unsigned h) {
    union { unsigned u; float f; } c; c.u = h << 16; return c.f;
}

union U8 { unsigned u[4]; bf16x8 v; };

__global__ void k_zero(int4* __restrict__ p, int n4) {
    int i = blockIdx.x * 256 + threadIdx.x;
    if (i < n4) p[i] = make_int4(0, 0, 0, 0);
}

// ---------------- CSR build ----------------
__global__ void k_hist(const int* __restrict__ key, int* __restrict__ deg, int E) {
    int e = blockIdx.x * 256 + threadIdx.x;
    if (e < E) atomicAdd(&deg[key[e]], 1);
}

__global__ void k_scan_block(const int* __restrict__ deg, int* __restrict__ rowptr,
                             int* __restrict__ bsum, int n) {
    __shared__ int lds[256];
    int tid = threadIdx.x;
    int base = blockIdx.x * 1024 + tid * 4;
    int v0 = base + 0 < n ? deg[base + 0] : 0;
    int v1 = base + 1 < n ? deg[base + 1] : 0;
    int v2 = base + 2 < n ? deg[base + 2] : 0;
    int v3 = base + 3 < n ? deg[base + 3] : 0;
    int tsum = v0 + v1 + v2 + v3;
    lds[tid] = tsum; __syncthreads();
    for (int off = 1; off < 256; off <<= 1) {
        int t = (tid >= off) ? lds[tid - off] : 0;
        __syncthreads();
        lds[tid] += t;
        __syncthreads();
    }
    int run = lds[tid] - tsum;
    if (base + 0 < n) rowptr[base + 0] = run; run += v0;
    if (base + 1 < n) rowptr[base + 1] = run; run += v1;
    if (base + 2 < n) rowptr[base + 2] = run; run += v2;
    if (base + 3 < n) rowptr[base + 3] = run;
    if (tid == 255) bsum[blockIdx.x] = lds[255];
}

__global__ void k_scan_tops(int* __restrict__ bsum, int nb) {
    __shared__ int lds[128];
    int tid = threadIdx.x;
    int v = tid < nb ? bsum[tid] : 0;
    lds[tid] = v; __syncthreads();
    for (int off = 1; off < 128; off <<= 1) {
        int t = (tid >= off) ? lds[tid - off] : 0;
        __syncthreads();
        lds[tid] += t;
        __syncthreads();
    }
    if (tid < nb) bsum[tid] = lds[tid] - v;
}

__global__ void k_scan_add(int* __restrict__ rowptr, const int* __restrict__ bsum, int n) {
    int i = blockIdx.x * 256 + threadIdx.x;
    if (i < n) rowptr[i] += bsum[i >> 10];
}

__global__ void k_dinv_bc(const int* __restrict__ deg, const int* __restrict__ cluster,
                          const int* __restrict__ inb, float* __restrict__ dinv,
                          int* __restrict__ bc, int n) {
    int i = blockIdx.x * 256 + threadIdx.x;
    if (i < n) {
        dinv[i] = rsqrtf((float)deg[i] + 1.0f);
        bc[i] = cluster[i] + inb[i] * NCLUST;
    }
}

__global__ void k_fill(const int* __restrict__ src, const int* __restrict__ dst,
                       const float* __restrict__ dinv, const int* __restrict__ rowptr,
                       int* __restrict__ fill, int* __restrict__ csr_src,
                       float* __restrict__ csr_w, int E) {
    int e = blockIdx.x * 256 + threadIdx.x;
    if (e >= E) return;
    int d = dst[e];
    int pos = rowptr[d] + atomicAdd(&fill[d], 1);
    int s = src[e];
    csr_src[pos] = s;
    csr_w[pos] = dinv[s];
}

__global__ void k_cfill(const int* __restrict__ bc, const int* __restrict__ crowptr,
                        int* __restrict__ cfill, int* __restrict__ cnodes, int n) {
    int i = blockIdx.x * 256 + threadIdx.x;
    if (i >= n) return;
    int c = bc[i];
    int pos = crowptr[c] + atomicAdd(&cfill[c], 1);
    cnodes[pos] = i;
}

// ------ GCN propagation, node-per-wave, edge-split, f32 in / f32 out ------
template <int F>
__global__ __launch_bounds__(256) void k_prop4s(
        const float* __restrict__ h, const float* __restrict__ dinv,
        const int* __restrict__ rowptr, const int* __restrict__ deg,
        const int* __restrict__ csr_src, const float* __restrict__ csr_w,
        const float* __restrict__ bias, float* __restrict__ out,
        int n, int flags) {
    constexpr int FS = F / 4;
    constexpr int ES = 64 / FS;
    const int node = (blockIdx.x * 256 + threadIdx.x) >> 6;
    if (node >= n) return;
    const int l = threadIdx.x & 63;
    const int fs = l & (FS - 1);
    const int ep = l / FS;
    const int fi = fs * 4;
    const int start = rowptr[node];
    const int cnt = deg[node];
    float ax = 0.f, ay = 0.f, az = 0.f, aw = 0.f;
    for (int j = ep; j < cnt; j += ES) {
        int s = csr_src[start + j];
        float w = csr_w[start + j];
        const float4 v = *reinterpret_cast<const float4*>(&h[(size_t)s * F + fi]);
        ax += w * v.x; ay += w * v.y; az += w * v.z; aw += w * v.w;
    }
#pragma unroll
    for (int off = FS; off < 64; off <<= 1) {
        ax += __shfl_xor(ax, off);
        ay += __shfl_xor(ay, off);
        az += __shfl_xor(az, off);
        aw += __shfl_xor(aw, off);
    }
    if (ep == 0) {
        float di = dinv[node];
        const float4 sv = *reinterpret_cast<const float4*>(&h[(size_t)node * F + fi]);
        float4 o;
        o.x = di * ax + di * di * sv.x;
        o.y = di * ay + di * di * sv.y;
        o.z = di * az + di * di * sv.z;
        o.w = di * aw + di * di * sv.w;
        if (flags) {
            const float4 b = *reinterpret_cast<const float4*>(&bias[fi]);
            o.x = elu1(o.x + b.x); o.y = elu1(o.y + b.y);
            o.z = elu1(o.z + b.z); o.w = elu1(o.w + b.w);
        }
        *reinterpret_cast<float4*>(&out[(size_t)node * F + fi]) = o;
    }
}

// ------ GCN propagation, bf16 input; OB=0 f32 out, OB=1 bf16 out ------
template <int F, int OB>
__global__ __launch_bounds__(256) void k_prop4sb(
        const unsigned short* __restrict__ hbf, const float* __restrict__ dinv,
        const int* __restrict__ rowptr, const int* __restrict__ deg,
        const int* __restrict__ csr_src, const float* __restrict__ csr_w,
        const float* __restrict__ bias, float* __restrict__ outf,
        unsigned short* __restrict__ outb, int n, int flags) {
    constexpr int FS = F / 4;
    constexpr int ES = 64 / FS;
    const int node = (blockIdx.x * 256 + threadIdx.x) >> 6;
    if (node >= n) return;
    const int l = threadIdx.x & 63;
    const int fs = l & (FS - 1);
    const int ep = l / FS;
    const int fi = fs * 4;
    const int start = rowptr[node];
    const int cnt = deg[node];
    float ax = 0.f, ay = 0.f, az = 0.f, aw = 0.f;
    for (int j = ep; j < cnt; j += ES) {
        int s = csr_src[start + j];
        float w = csr_w[start + j];
        const ushort4 v = *reinterpret_cast<const ushort4*>(&hbf[(size_t)s * F + fi]);
        ax += w * bf2f(v.x); ay += w * bf2f(v.y);
        az += w * bf2f(v.z); aw += w * bf2f(v.w);
    }
#pragma unroll
    for (int off = FS; off < 64; off <<= 1) {
        ax += __shfl_xor(ax, off);
        ay += __shfl_xor(ay, off);
        az += __shfl_xor(az, off);
        aw += __shfl_xor(aw, off);
    }
    if (ep == 0) {
        float di = dinv[node];
        const ushort4 sv = *reinterpret_cast<const ushort4*>(&hbf[(size_t)node * F + fi]);
        float4 o;
        o.x = di * ax + di * di * bf2f(sv.x);
        o.y = di * ay + di * di * bf2f(sv.y);
        o.z = di * az + di * di * bf2f(sv.z);
        o.w = di * aw + di * di * bf2f(sv.w);
        if (flags) {
            const float4 b = *reinterpret_cast<const float4*>(&bias[fi]);
            o.x = elu1(o.x + b.x); o.y = elu1(o.y + b.y);
            o.z = elu1(o.z + b.z); o.w = elu1(o.w + b.w);
        }
        if constexpr (OB) {
            ushort4 ob;
            ob.x = (unsigned short)f2bf(o.x); ob.y = (unsigned short)f2bf(o.y);
            ob.z = (unsigned short)f2bf(o.z); ob.w = (unsigned short)f2bf(o.w);
            *reinterpret_cast<ushort4*>(&outb[(size_t)node * F + fi]) = ob;
        } else {
            *reinterpret_cast<float4*>(&outf[(size_t)node * F + fi]) = o;
        }
    }
}

__global__ void k_prop3(const float* __restrict__ h, const float* __restrict__ dinv,
                        const int* __restrict__ rowptr, const int* __restrict__ deg,
                        const int* __restrict__ csr_src, const float* __restrict__ csr_w,
                        const float* __restrict__ bias, float* __restrict__ out,
                        int n, int flags) {
    int node = blockIdx.x * 256 + threadIdx.x;
    if (node >= n) return;
    int start = rowptr[node], cnt = deg[node];
    float a0 = 0.f, a1 = 0.f, a2 = 0.f;
    for (int j = 0; j < cnt; j++) {
        int s = csr_src[start + j];
        float w = csr_w[start + j];
        a0 += w * h[(size_t)s * 3 + 0];
        a1 += w * h[(size_t)s * 3 + 1];
        a2 += w * h[(size_t)s * 3 + 2];
    }
    float di = dinv[node];
    float o0 = di * a0 + di * di * h[(size_t)node * 3 + 0];
    float o1 = di * a1 + di * di * h[(size_t)node * 3 + 1];
    float o2 = di * a2 + di * di * h[(size_t)node * 3 + 2];
    if (flags) {
        o0 = elu1(o0 + bias[0]); o1 = elu1(o1 + bias[1]); o2 = elu1(o2 + bias[2]);
    }
    out[(size_t)node * 3 + 0] = o0;
    out[(size_t)node * 3 + 1] = o1;
    out[(size_t)node * 3 + 2] = o2;
}

// ---- W pre-pack to MFMA fragment order (hi/lo bf16), optional row scale ----
__global__ void k_wpack(const float* __restrict__ W, const float* __restrict__ scale,
                        unsigned* __restrict__ Phi, unsigned* __restrict__ Plo,
                        int K, int BN) {
    int t = blockIdx.x * 256 + threadIdx.x;
    int NT = BN / 16;
    int total = (K / 32) * NT * 64;
    if (t >= total) return;
    int lane = t & 63;
    int rest = t >> 6;
    int ct = rest % NT;
    int s = rest / NT;
    int col = ct * 16 + (lane & 15);
    int g = lane >> 4;
    int k0 = s * 32;
    float e[8];
#pragma unroll
    for (int j = 0; j < 4; j++) {
        int ka = k0 + 4 * g + j;
        int kb = k0 + 16 + 4 * g + j;
        float sa = scale ? scale[ka] : 1.f;
        float sb = scale ? scale[kb] : 1.f;
        e[j]     = W[(size_t)ka * BN + col] * sa;
        e[4 + j] = W[(size_t)kb * BN + col] * sb;
    }
#pragma unroll
    for (int j = 0; j < 4; j++) {
        unsigned h0 = f2bf(e[2 * j]), h1 = f2bf(e[2 * j + 1]);
        Phi[(size_t)t * 4 + j] = h0 | (h1 << 16);
        unsigned l0 = f2bf(e[2 * j] - bf2f(h0));
        unsigned l1 = f2bf(e[2 * j + 1] - bf2f(h1));
        Plo[(size_t)t * 4 + j] = l0 | (l1 << 16);
    }
}

// corr[c] += partial rank-1 instance-norm correction
__global__ void k_corr(const float* __restrict__ W, const float* __restrict__ mu,
                       const float* __restrict__ rstd, float* __restrict__ corr,
                       int M) {
    int c = threadIdx.x;
    if (c >= M) return;
    int k0 = blockIdx.x * 16;
    float s = 0.f;
    for (int k = k0; k < k0 + 16; k++) s += mu[k] * rstd[k] * W[(size_t)k * M + c];
    atomicAdd(&corr[c], s);
}

// ---- split-bf16 MFMA GEMM, 2-stage software pipeline ----
// ABF=false: A f32, split into hi/lo (3 MFMAs/frag-pair).
// ABF=true: A pre-converted bf16 (2 MFMAs). Ping-pong register buffers
// prefetch k-step s+1 before s's MFMAs (explicit names: no dynamic indexing).
template <int BN, bool ABF>
__global__ __launch_bounds__(256) void k_gmfma(
        const float* __restrict__ A, const unsigned short* __restrict__ Abf,
        const unsigned* __restrict__ Phi, const unsigned* __restrict__ Plo,
        const float* __restrict__ bias, const float* __restrict__ sub,
        const float* __restrict__ add, const int* __restrict__ addidx,
        float* __restrict__ C, unsigned short* __restrict__ Cbf,
        int N, int K, int flags) {
    constexpr int NT = BN / 16;
    constexpr int WCOL = (BN == 256) ? 4 : (BN == 128 ? 2 : 1);
    constexpr int WROW = 4 / WCOL;
    constexpr int NTW = NT / WCOL;
    constexpr int BR = 32 * WROW;
    const int t = threadIdx.x;
    const int w = t >> 6, l = t & 63;
    const int wr = w / WCOL, wc = w % WCOL;
    const int l15 = l & 15, g = l >> 4;
    const int row0 = blockIdx.x * BR + wr * 32;
    const int ctbase = wc * NTW;
    int ar0 = row0 + l15;      ar0 = ar0 < N ? ar0 : N - 1;
    int ar1 = row0 + 16 + l15; ar1 = ar1 < N ? ar1 : N - 1;
    const float* ap0 = ABF ? nullptr : A + (size_t)ar0 * K;
    const float* ap1 = ABF ? nullptr : A + (size_t)ar1 * K;
    const unsigned short* ab0 = ABF ? Abf + (size_t)ar0 * K : nullptr;
    const unsigned short* ab1 = ABF ? Abf + (size_t)ar1 * K : nullptr;

    f32x4 acc[2][NTW];
#pragma unroll
    for (int f = 0; f < 2; f++)
#pragma unroll
        for (int ct = 0; ct < NTW; ct++) acc[f][ct] = (f32x4){0.f, 0.f, 0.f, 0.f};

    auto loadW = [&](int s, U8* wh, U8* wl) {
        const unsigned* pb = Phi + ((size_t)(s * NT + ctbase) * 64 + l) * 4;
        const unsigned* pl = Plo + ((size_t)(s * NT + ctbase) * 64 + l) * 4;
#pragma unroll
        for (int ct = 0; ct < NTW; ct++) {
            wh[ct] = *reinterpret_cast<const U8*>(pb + (size_t)ct * 256);
            wl[ct] = *reinterpret_cast<const U8*>(pl + (size_t)ct * 256);
        }
    };
    auto loadA = [&](int s, U8* ahi, U8* alo) {
        const int k0 = s * 32;
        if constexpr (ABF) {
#pragma unroll
            for (int f = 0; f < 2; f++) {
                const unsigned short* ab = f ? ab1 : ab0;
                const uint2 hA = *reinterpret_cast<const uint2*>(ab + k0 + 4 * g);
                const uint2 hB = *reinterpret_cast<const uint2*>(ab + k0 + 16 + 4 * g);
                ahi[f].u[0] = hA.x; ahi[f].u[1] = hA.y;
                ahi[f].u[2] = hB.x; ahi[f].u[3] = hB.y;
            }
        } else {
#pragma unroll
            for (int f = 0; f < 2; f++) {
                const float* ap = f ? ap1 : ap0;
                const float4 a0 = *reinterpret_cast<const float4*>(ap + k0 + 4 * g);
                const float4 a1 = *reinterpret_cast<const float4*>(ap + k0 + 16 + 4 * g);
                float e[8] = {a0.x, a0.y, a0.z, a0.w, a1.x, a1.y, a1.z, a1.w};
#pragma unroll
                for (int j = 0; j < 4; j++) {
                    unsigned h0 = f2bf(e[2 * j]), h1 = f2bf(e[2 * j + 1]);
                    ahi[f].u[j] = h0 | (h1 << 16);
                    unsigned l0 = f2bf(e[2 * j] - bf2f(h0));
                    unsigned l1 = f2bf(e[2 * j + 1] - bf2f(h1));
                    alo[f].u[j] = l0 | (l1 << 16);
                }
            }
        }
    };
    auto domfma = [&](U8* wh, U8* wl, U8* ahi, U8* alo) {
#pragma unroll
        for (int ct = 0; ct < NTW; ct++) {
            acc[0][ct] = __builtin_amdgcn_mfma_f32_16x16x32_bf16(ahi[0].v, wh[ct].v, acc[0][ct], 0, 0, 0);
            acc[0][ct] = __builtin_amdgcn_mfma_f32_16x16x32_bf16(ahi[0].v, wl[ct].v, acc[0][ct], 0, 0, 0);
            acc[1][ct] = __builtin_amdgcn_mfma_f32_16x16x32_bf16(ahi[1].v, wh[ct].v, acc[1][ct], 0, 0, 0);
            acc[1][ct] = __builtin_amdgcn_mfma_f32_16x16x32_bf16(ahi[1].v, wl[ct].v, acc[1][ct], 0, 0, 0);
            if constexpr (!ABF) {
                acc[0][ct] = __builtin_amdgcn_mfma_f32_16x16x32_bf16(alo[0].v, wh[ct].v, acc[0][ct], 0, 0, 0);
                acc[1][ct] = __builtin_amdgcn_mfma_f32_16x16x32_bf16(alo[1].v, wh[ct].v, acc[1][ct], 0, 0, 0);
            }
        }
    };

    U8 whA[NTW], wlA[NTW], ahiA[2], aloA[2];
    U8 whB[NTW], wlB[NTW], ahiB[2], aloB[2];
    const int nk = K / 32;
    loadW(0, whA, wlA);
    loadA(0, ahiA, aloA);
    int s = 0;
    while (true) {
        const bool hasB = (s + 1 < nk);
        if (hasB) { loadW(s + 1, whB, wlB); loadA(s + 1, ahiB, aloB); }
        domfma(whA, wlA, ahiA, aloA);
        if (!hasB) break;
        const bool hasA2 = (s + 2 < nk);
        if (hasA2) { loadW(s + 2, whA, wlA); loadA(s + 2, ahiA, aloA); }
        domfma(whB, wlB, ahiB, aloB);
        if (!hasA2) break;
        s += 2;
    }
    __syncthreads();   // all A reads done before any store (in-place safe)
#pragma unroll
    for (int f = 0; f < 2; f++) {
#pragma unroll
        for (int r = 0; r < 4; r++) {
            int row = row0 + 16 * f + 4 * g + r;
            if (row >= N) continue;
            int gi = (add != nullptr) ? addidx[row] : 0;
#pragma unroll
            for (int ct = 0; ct < NTW; ct++) {
                int col = (ctbase + ct) * 16 + l15;
                float o = acc[f][ct][r];
                if (add != nullptr) o += add[(size_t)gi * BN + col];
                if (sub != nullptr) o -= sub[col];
                if (flags) o = elu1(o + bias[col]);
                if (C != nullptr) C[(size_t)row * BN + col] = o;
                if (Cbf != nullptr) Cbf[(size_t)row * BN + col] = (unsigned short)f2bf(o);
            }
        }
    }
}

// ---------------- simple fc (small shapes) ----------------
template <int M, int RPT>
__global__ __launch_bounds__(256) void k_fc(
        const float* __restrict__ A, const float* __restrict__ W,
        const float* __restrict__ bias, const float* __restrict__ add,
        const int* __restrict__ addidx, float* __restrict__ C,
        int N, int K, int flags) {
    constexpr int TX = M / 4;
    constexpr int TY = 256 / TX;
    constexpr int RB = TY * RPT;
    int tx = threadIdx.x % TX;
    int ty = threadIdx.x / TX;
    int row0 = blockIdx.x * RB + ty * RPT;
    float4 acc[RPT];
#pragma unroll
    for (int r = 0; r < RPT; r++) acc[r] = make_float4(0.f, 0.f, 0.f, 0.f);
    for (int k = 0; k < K; k++) {
        float4 w = *reinterpret_cast<const float4*>(&W[(size_t)k * M + tx * 4]);
#pragma unroll
        for (int r = 0; r < RPT; r++) {
            int row = row0 + r;
            row = row < N ? row : N - 1;
            float a = A[(size_t)row * K + k];
            acc[r].x += a * w.x; acc[r].y += a * w.y;
            acc[r].z += a * w.z; acc[r].w += a * w.w;
        }
    }
    if (add != nullptr) {
#pragma unroll
        for (int r = 0; r < RPT; r++) {
            int row = row0 + r;
            if (row < N) {
                int g = addidx[row];
                const float4 v = *reinterpret_cast<const float4*>(&add[(size_t)g * M + tx * 4]);
                acc[r].x += v.x; acc[r].y += v.y; acc[r].z += v.z; acc[r].w += v.w;
            }
        }
    }
    __syncthreads();
    float4 b = make_float4(0.f, 0.f, 0.f, 0.f);
    if (flags) b = *reinterpret_cast<const float4*>(&bias[tx * 4]);
#pragma unroll
    for (int r = 0; r < RPT; r++) {
        int row = row0 + r;
        if (row >= N) break;
        float4 o = acc[r];
        o.x += b.x; o.y += b.y; o.z += b.z; o.w += b.w;
        if (flags) { o.x = elu1(o.x); o.y = elu1(o.y); o.z = elu1(o.z); o.w = elu1(o.w); }
        *reinterpret_cast<float4*>(&C[(size_t)row * M + tx * 4]) = o;
    }
}

__global__ void k_fc3(const float* __restrict__ A, const float* __restrict__ W,
                      const float* __restrict__ b, float* __restrict__ C,
                      int n, int K, int flags) {
    int r = blockIdx.x * 256 + threadIdx.x;
    if (r >= n) return;
    float a0 = 0.f, a1 = 0.f, a2 = 0.f;
    for (int k = 0; k < K; k++) {
        float a = A[(size_t)r * K + k];
        a0 += a * W[k * 3 + 0]; a1 += a * W[k * 3 + 1]; a2 += a * W[k * 3 + 2];
    }
    if (flags) {
        a0 = elu1(a0 + b[0]); a1 = elu1(a1 + b[1]); a2 = elu1(a2 + b[2]);
    }
    C[(size_t)r * 3 + 0] = a0;
    C[(size_t)r * 3 + 1] = a1;
    C[(size_t)r * 3 + 2] = a2;
}

// ---------------- instance norm stats (bf16 input) ----------------
__global__ void k_instats(const unsigned short* __restrict__ h, float* __restrict__ sum,
                          float* __restrict__ sumsq, int n) {
    int c = threadIdx.x;
    int r0 = blockIdx.x * 128;
    int r1 = r0 + 128 < n ? r0 + 128 : n;
    float s = 0.f, q = 0.f;
    for (int r = r0; r < r1; r++) {
        float v = bf2f(h[(size_t)r * 256 + c]);
        s += v; q += v * v;
    }
    atomicAdd(&sum[c], s);
    atomicAdd(&sumsq[c], q);
}

__global__ void k_infinal(const float* __restrict__ sum, const float* __restrict__ sumsq,
                          float* __restrict__ mu, float* __restrict__ rstd, int n) {
    int c = threadIdx.x;
    float m = sum[c] / (float)n;
    float var = sumsq[c] / (float)n - m * m;
    mu[c] = m;
    rstd[c] = rsqrtf(var + 1e-5f);
}

// ---------------- cluster pooling (bf16 input, normalize in epilogue) -------
__global__ __launch_bounds__(256) void k_poolavg(
        const unsigned short* __restrict__ xh, const int* __restrict__ crowptr,
        const int* __restrict__ cdeg, const int* __restrict__ cnodes,
        const float* __restrict__ mu, const float* __restrict__ rstd,
        float* __restrict__ px) {
    int cl = blockIdx.x;
    int c  = threadIdx.x;
    int start = crowptr[cl];
    int cnt = cdeg[cl];
    float acc = 0.f;
    for (int j = 0; j < cnt; j++) {
        int node = cnodes[start + j];
        acc += bf2f(xh[(size_t)node * 256 + c]);
    }
    float res = acc / fmaxf((float)cnt, 1.0f);
    res = (cnt > 0) ? (res - mu[c]) * rstd[c] : 0.f;
    px[(size_t)cl * 256 + c] = res;
}

__global__ void k_pooledges(const int* __restrict__ src, const int* __restrict__ dst,
                            const int* __restrict__ bc, unsigned char* __restrict__ bmT, int E) {
    int e = blockIdx.x * 256 + threadIdx.x;
    if (e >= E) return;
    int ps = bc[src[e]];
    int pd = bc[dst[e]];
    bmT[(size_t)pd * NCLUST + ps] = 1;
}

__global__ __launch_bounds__(256) void k_pooldeg(
        const unsigned char* __restrict__ bmT, float* __restrict__ dinvp) {
    int d = blockIdx.x;
    int t = threadIdx.x;
    const unsigned int v = reinterpret_cast<const unsigned int*>(bmT + (size_t)d * NCLUST)[t];
    int s = (v & 0xff) + ((v >> 8) & 0xff) + ((v >> 16) & 0xff) + ((v >> 24) & 0xff);
    if (t == (d >> 2)) s -= (v >> ((d & 3) * 8)) & 0xff;
    __shared__ int red[256];
    red[t] = s; __syncthreads();
    for (int o = 128; o > 0; o >>= 1) {
        if (t < o) red[t] += red[t + o];
        __syncthreads();
    }
    if (t == 0) dinvp[d] = rsqrtf((float)red[0] + 1.0f);
}

template <int F>
__global__ __launch_bounds__(1024) void k_proppool2(
        const float* __restrict__ h, const float* __restrict__ dinvp,
        const unsigned char* __restrict__ bmT, const float* __restrict__ bias,
        float* __restrict__ out) {
    constexpr int SG = 1024 / F;
    const int d = blockIdx.x;
    const int t = threadIdx.x;
    const int f = t & (F - 1);
    const int sg = t / F;
    const unsigned char* bmrow = bmT + (size_t)d * NCLUST;
    float acc = 0.f;
#pragma unroll 4
    for (int s = sg; s < NCLUST; s += SG) {
        float m = (s != d) ? (float)bmrow[s] : 0.f;
        acc += m * dinvp[s] * h[(size_t)s * F + f];
    }
    __shared__ float red[1024];
    red[t] = acc; __syncthreads();
#pragma unroll
    for (int o = SG / 2; o > 0; o >>= 1) {
        if (sg < o) red[t] += red[t + o * F];
        __syncthreads();
    }
    if (sg == 0) {
        float di = dinvp[d];
        float r = di * red[f] + di * di * h[(size_t)d * F + f] + bias[f];
        out[(size_t)d * F + f] = elu1(r);
    }
}

// ---------------------------------------------------------------------------
extern "C" void kernel_launch(void* const* d_in, const int* in_sizes, int n_in,
                              void* d_out, int out_size, void* d_ws, size_t ws_size,
                              hipStream_t stream) {
    const float* x       = (const float*)d_in[0];
    const int*   adj     = (const int*)d_in[1];
    const int*   inb     = (const int*)d_in[3];
    const int*   cluster = (const int*)d_in[4];
    const float* WG1  = (const float*)d_in[5];   const float* bG1  = (const float*)d_in[6];
    const float* WfG1 = (const float*)d_in[7];   const float* bfG1 = (const float*)d_in[8];
    const float* WG2  = (const float*)d_in[9];   const float* bG2  = (const float*)d_in[10];
    const float* WfG2 = (const float*)d_in[11];  const float* bfG2 = (const float*)d_in[12];
    const float* WL1  = (const float*)d_in[13];  const float* bL1  = (const float*)d_in[14];
    const float* WfL1 = (const float*)d_in[15];  const float* bfL1 = (const float*)d_in[16];
    const float* WL2  = (const float*)d_in[17];  const float* bL2  = (const float*)d_in[18];
    const float* WfL2 = (const float*)d_in[19];  const float* bfL2 = (const float*)d_in[20];
    const float* WO1  = (const float*)d_in[21];  const float* bO1  = (const float*)d_in[22];
    const float* WfO1 = (const float*)d_in[23];  const float* bfO1 = (const float*)d_in[24];
    const float* WO2  = (const float*)d_in[25];  const float* bO2  = (const float*)d_in[26];
    const float* WfO2 = (const float*)d_in[27];  const float* bfO2 = (const float*)d_in[28];
    const float* WO3  = (const float*)d_in[29];  const float* bO3  = (const float*)d_in[30];
    const float* WfO3 = (const float*)d_in[31];  const float* bfO3 = (const float*)d_in[32];
    float* out = (float*)d_out;

    const int n = in_sizes[0] / 3;       // 100000
    const int E = in_sizes[1] / 2;       // 1600000
    const int* src = adj;
    const int* dst = adj + E;

    // ---- workspace carve (~250 MB) ----
    char* ws = (char*)d_ws;
    size_t off = 0;
    auto alloc = [&](size_t bytes) -> void* {
        void* p = ws + off;
        off = (off + bytes + 255) & ~(size_t)255;
        return p;
    };
    int*   deg     = (int*)alloc((size_t)n * 4);     // zero span 1 start
    int*   fill    = (int*)alloc((size_t)n * 4);
    int*   cdeg    = (int*)alloc(NCLUST * 4);
    int*   cfill   = (int*)alloc(NCLUST * 4);
    int*   rowptr  = (int*)alloc((size_t)n * 4);     // zero span 1 end (exclusive)
    int*   crowptr = (int*)alloc(NCLUST * 4);
    int*   cnodes  = (int*)alloc((size_t)n * 4);
    int*   bcarr   = (int*)alloc((size_t)n * 4);
    float* dinv    = (float*)alloc((size_t)n * 4);
    int*   bsum    = (int*)alloc(512);
    int*   csr_src = (int*)alloc((size_t)E * 4);
    float* csr_w   = (float*)alloc((size_t)E * 4);
    float* X       = (float*)alloc((size_t)n * 256 * 4);
    unsigned short* Xh = (unsigned short*)alloc((size_t)n * 256 * 2);  // bf16 act
    float* B       = (float*)alloc((size_t)n * 128 * 4);
    unsigned short* Bh = (unsigned short*)alloc((size_t)n * 128 * 2);  // bf16 t1/t2
    float* insum   = (float*)alloc(256 * 4);         // zero span 2 start
    float* insumsq = (float*)alloc(256 * 4);
    float* px      = (float*)alloc((size_t)NCLUST * 256 * 4);
    unsigned char* bmT = (unsigned char*)alloc((size_t)NCLUST * NCLUST);
    float* corr    = (float*)alloc(128 * 4);
    float* mu      = (float*)alloc(256 * 4);         // zero span 2 end (exclusive)
    float* rstd    = (float*)alloc(256 * 4);
    float* dinvp   = (float*)alloc(NCLUST * 4);
    float* lA      = (float*)alloc((size_t)NCLUST * 128 * 4);
    float* lB      = (float*)alloc((size_t)NCLUST * 128 * 4);
    unsigned* pfG1h = (unsigned*)alloc(2048 * 4);   unsigned* pfG1l = (unsigned*)alloc(2048 * 4);
    unsigned* pG2h  = (unsigned*)alloc(8192 * 4);   unsigned* pG2l  = (unsigned*)alloc(8192 * 4);
    unsigned* pfG2h = (unsigned*)alloc(32768 * 4);  unsigned* pfG2l = (unsigned*)alloc(32768 * 4);
    unsigned* pO1h  = (unsigned*)alloc(16384 * 4);  unsigned* pO1l  = (unsigned*)alloc(16384 * 4);
    unsigned* pfO1h = (unsigned*)alloc(8192 * 4);   unsigned* pfO1l = (unsigned*)alloc(8192 * 4);
    unsigned* pO2h  = (unsigned*)alloc(2048 * 4);   unsigned* pO2l  = (unsigned*)alloc(2048 * 4);
    unsigned* pfO2h = (unsigned*)alloc(512 * 4);    unsigned* pfO2l = (unsigned*)alloc(512 * 4);
    (void)ws_size; (void)n_in; (void)out_size;

    float* B0 = B;
    float* B1 = B + (size_t)n * 64;

    auto cdiv = [](int a, int b) { return (a + b - 1) / b; };
    const int EB = cdiv(E, 256);
    const int GB32 = cdiv(n, 32);        // gmfma grid, BN=256
    const int GB64 = cdiv(n, 64);        // gmfma grid, BN=128
    const int GB128 = cdiv(n, 128);      // gmfma grid, BN<=64
    const int PB = cdiv(n, 4);           // prop grid (node per wave)

    // ---- zero scratch ----
    int nz1 = (int)(((char*)rowptr - (char*)deg) / 16);
    int nz2 = (int)(((char*)mu - (char*)insum) / 16);
    k_zero<<<cdiv(nz1, 256), 256, 0, stream>>>((int4*)deg, nz1);
    k_zero<<<cdiv(nz2, 256), 256, 0, stream>>>((int4*)insum, nz2);

    // ---- pack weights (WO1 packed later, rstd-scaled) ----
    k_wpack<<<cdiv(512, 256), 256, 0, stream>>>(WfG1, nullptr, pfG1h, pfG1l, 64, 64);
    k_wpack<<<cdiv(2048, 256), 256, 0, stream>>>(WG2, nullptr, pG2h, pG2l, 64, 256);
    k_wpack<<<cdiv(8192, 256), 256, 0, stream>>>(WfG2, nullptr, pfG2h, pfG2l, 256, 256);
    k_wpack<<<cdiv(2048, 256), 256, 0, stream>>>(WfO1, nullptr, pfO1h, pfO1l, 128, 128);
    k_wpack<<<cdiv(512, 256), 256, 0, stream>>>(WO2, nullptr, pO2h, pO2l, 128, 32);
    k_wpack<<<cdiv(128, 256), 256, 0, stream>>>(WfO2, nullptr, pfO2h, pfO2l, 32, 32);

    // ---- CSR build (edges) ----
    k_hist<<<EB, 256, 0, stream>>>(dst, deg, E);
    int nb = cdiv(n, 1024);
    k_scan_block<<<nb, 256, 0, stream>>>(deg, rowptr, bsum, n);
    k_scan_tops<<<1, 128, 0, stream>>>(bsum, nb);
    k_scan_add<<<cdiv(n, 256), 256, 0, stream>>>(rowptr, bsum, n);
    k_dinv_bc<<<cdiv(n, 256), 256, 0, stream>>>(deg, cluster, inb, dinv, bcarr, n);
    k_fill<<<EB, 256, 0, stream>>>(src, dst, dinv, rowptr, fill, csr_src, csr_w, E);

    // ---- CSR build (cluster member lists) ----
    k_hist<<<cdiv(n, 256), 256, 0, stream>>>(bcarr, cdeg, n);
    k_scan_block<<<1, 256, 0, stream>>>(cdeg, crowptr, bsum, NCLUST);
    k_cfill<<<cdiv(n, 256), 256, 0, stream>>>(bcarr, crowptr, cfill, cnodes, n);

    // ---- global GCN stack ----
    k_prop3<<<cdiv(n, 256), 256, 0, stream>>>(x, dinv, rowptr, deg, csr_src, csr_w,
                                              nullptr, B0, n, 0);
    k_fc<64, 2><<<cdiv(n, 32), 256, 0, stream>>>(B0, WG1, bG1, nullptr, nullptr, B1, n, 3, 1);
    // h2 = elu(h1 @ WfG1 + bfG1)  (B1 in-place, f32-A mode)
    k_gmfma<64, false><<<GB128, 256, 0, stream>>>(B1, nullptr, pfG1h, pfG1l, bfG1,
                                                  nullptr, nullptr, nullptr, B1, nullptr,
                                                  n, 64, 1);
    k_prop4s<64><<<PB, 256, 0, stream>>>(B1, dinv, rowptr, deg, csr_src, csr_w,
                                         nullptr, B0, n, 0);
    // h3 = elu(p64 @ WG2 + bG2)  -> bf16 ONLY (Xh)
    k_gmfma<256, false><<<GB32, 256, 0, stream>>>(B0, nullptr, pG2h, pG2l, bG2,
                                                  nullptr, nullptr, nullptr, nullptr, Xh,
                                                  n, 64, 1);
    // h4 = elu(h3 @ WfG2 + bfG2)  (bf16-A, Xh in-place, bf16 ONLY out)
    k_gmfma<256, true><<<GB32, 256, 0, stream>>>(nullptr, Xh, pfG2h, pfG2l, bfG2,
                                                 nullptr, nullptr, nullptr, nullptr, Xh,
                                                 n, 256, 1);

    // ---- instance norm stats from bf16 Xh ----
    k_instats<<<cdiv(n, 128), 256, 0, stream>>>(Xh, insum, insumsq, n);
    k_infinal<<<1, 256, 0, stream>>>(insum, insumsq, mu, rstd, n);
    k_wpack<<<cdiv(4096, 256), 256, 0, stream>>>(WO1, rstd, pO1h, pO1l, 256, 128);
    k_corr<<<16, 128, 0, stream>>>(WO1, mu, rstd, corr, 128);

    // ---- cluster pooling (bf16 Xh + affine fixup in epilogue) ----
    k_poolavg<<<NCLUST, 256, 0, stream>>>(Xh, crowptr, cdeg, cnodes, mu, rstd, px);
    k_pooledges<<<EB, 256, 0, stream>>>(src, dst, bcarr, bmT, E);
    k_pooldeg<<<NCLUST, 256, 0, stream>>>(bmT, dinvp);

    // ---- local (pooled) GCN stack ----
    k_fc<128, 2><<<cdiv(NCLUST, 16), 256, 0, stream>>>(px, WL1, nullptr, nullptr, nullptr,
                                                       lA, NCLUST, 256, 0);
    k_proppool2<128><<<NCLUST, 1024, 0, stream>>>(lA, dinvp, bmT, bL1, lB);
    k_fc<128, 2><<<cdiv(NCLUST, 16), 256, 0, stream>>>(lB, WfL1, bfL1, nullptr, nullptr,
                                                       lA, NCLUST, 128, 1);
    k_fc<64, 2><<<cdiv(NCLUST, 32), 256, 0, stream>>>(lA, WL2, nullptr, nullptr, nullptr,
                                                      lB, NCLUST, 128, 0);
    k_proppool2<64><<<NCLUST, 1024, 0, stream>>>(lB, dinvp, bmT, bL2, lA);
    k_fc<64, 2><<<cdiv(NCLUST, 32), 256, 0, stream>>>(lA, WfL2, bfL2, nullptr, nullptr,
                                                      lB, NCLUST, 64, 1);
    k_fc<128, 2><<<cdiv(NCLUST, 16), 256, 0, stream>>>(lB, WO1 + (size_t)256 * 128, nullptr,
                                                       nullptr, nullptr, lA, NCLUST, 64, 0);

    // ---- output GCN stack ----
    // t1 = Xh @ (rstd*WO1) - corr + compO[bc]  -> bf16 (Bh)
    k_gmfma<128, true><<<GB64, 256, 0, stream>>>(nullptr, Xh, pO1h, pO1l, nullptr,
                                                 corr, lA, bcarr, nullptr, Bh,
                                                 n, 256, 0);
    // o1 = elu(S t1 + bO1)  -> bf16 (Xh, stride 128)
    k_prop4sb<128, 1><<<PB, 256, 0, stream>>>(Bh, dinv, rowptr, deg, csr_src, csr_w,
                                              bO1, nullptr, Xh, n, 1);
    // o2 = elu(o1 @ WfO1 + bfO1)  (bf16-A, Xh in-place)
    k_gmfma<128, true><<<GB64, 256, 0, stream>>>(nullptr, Xh, pfO1h, pfO1l, bfO1,
                                                 nullptr, nullptr, nullptr, nullptr, Xh,
                                                 n, 128, 1);
    // t2 = o2 @ WO2  -> bf16 (Bh, N x 32)
    k_gmfma<32, true><<<GB128, 256, 0, stream>>>(nullptr, Xh, pO2h, pO2l, nullptr,
                                                 nullptr, nullptr, nullptr, nullptr, Bh,
                                                 n, 128, 0);
    // o3 = elu(S t2 + bO2)  -> bf16 (Xh, stride 32)
    k_prop4sb<32, 1><<<PB, 256, 0, stream>>>(Bh, dinv, rowptr, deg, csr_src, csr_w,
                                             bO2, nullptr, Xh, n, 1);
    // o4 = elu(o3 @ WfO2 + bfO2)  (bf16-A, f32 out X)
    k_gmfma<32, true><<<GB128, 256, 0, stream>>>(nullptr, Xh, pfO2h, pfO2l, bfO2,
                                                 nullptr, nullptr, nullptr, X, nullptr,
                                                 n, 32, 1);
    k_fc3<<<cdiv(n, 256), 256, 0, stream>>>(X, WO3, nullptr, B, n, 32, 0);
    k_prop3<<<cdiv(n, 256), 256, 0, stream>>>(B, dinv, rowptr, deg, csr_src, csr_w,
                                              bO3, X, n, 1);
    k_fc3<<<cdiv(n, 256), 256, 0, stream>>>(X, WfO3, bfO3, out, n, 3, 1);
}

// Round 17
// 1254.651 us; speedup vs baseline: 1.0456x; 1.0456x over previous
//
#include <hip/hip_runtime.h>

// ---------------------------------------------------------------------------
// GCN3D. R9: split-bf16 MFMA GEMMs. R12: NTW=4. R13: prop4s+norm-fold.
// R14/15: bf16 activations for late stack. R16: 2-stage pipelined GEMM.
// R17: wall-time is ~40% inter-kernel overhead (~49 launches x ~10us):
//   (a) merge 6 wpacks into k_wpack_all; merge 2 zeros; merge
//       scan_add+dinv_bc+cluster-hist into k_nodeinit  (-8 launches);
//   (b) h2 emits bf16 -> p64 prop gathers bf16 (410->205MB).
// ---------------------------------------------------------------------------

#define NCLUST 1024

typedef short bf16x8 __attribute__((ext_vector_type(8)));
typedef float f32x4 __attribute__((ext_vector_type(4)));

__device__ __forceinline__ float elu1(float x) { return x > 0.f ? x : expm1f(x); }

__device__ __forceinline__ unsigned f2bf(float f) {
    union { float f; unsigned u; } c; c.f = f;
    unsigned u = c.u;
    return (u + 0x7fffu + ((u >> 16) & 1u)) >> 16;
}
__device__ __forceinline__ float bf2f(unsigned h) {
    union { unsigned u; float f; } c; c.u = h << 16; return c.f;
}

union U8 { unsigned u[4]; bf16x8 v; };

// one launch zeroes both scratch spans
__global__ void k_zero2(int4* __restrict__ p1, int n1, int4* __restrict__ p2, int n2) {
    int i = blockIdx.x * 256 + threadIdx.x;
    if (i < n1) p1[i] = make_int4(0, 0, 0, 0);
    else if (i - n1 < n2) p2[i - n1] = make_int4(0, 0, 0, 0);
}

// ---------------- CSR build ----------------
__global__ void k_hist(const int* __restrict__ key, int* __restrict__ deg, int E) {
    int e = blockIdx.x * 256 + threadIdx.x;
    if (e < E) atomicAdd(&deg[key[e]], 1);
}

__global__ void k_scan_block(const int* __restrict__ deg, int* __restrict__ rowptr,
                             int* __restrict__ bsum, int n) {
    __shared__ int lds[256];
    int tid = threadIdx.x;
    int base = blockIdx.x * 1024 + tid * 4;
    int v0 = base + 0 < n ? deg[base + 0] : 0;
    int v1 = base + 1 < n ? deg[base + 1] : 0;
    int v2 = base + 2 < n ? deg[base + 2] : 0;
    int v3 = base + 3 < n ? deg[base + 3] : 0;
    int tsum = v0 + v1 + v2 + v3;
    lds[tid] = tsum; __syncthreads();
    for (int off = 1; off < 256; off <<= 1) {
        int t = (tid >= off) ? lds[tid - off] : 0;
        __syncthreads();
        lds[tid] += t;
        __syncthreads();
    }
    int run = lds[tid] - tsum;
    if (base + 0 < n) rowptr[base + 0] = run; run += v0;
    if (base + 1 < n) rowptr[base + 1] = run; run += v1;
    if (base + 2 < n) rowptr[base + 2] = run; run += v2;
    if (base + 3 < n) rowptr[base + 3] = run;
    if (tid == 255) bsum[blockIdx.x] = lds[255];
}

__global__ void k_scan_tops(int* __restrict__ bsum, int nb) {
    __shared__ int lds[128];
    int tid = threadIdx.x;
    int v = tid < nb ? bsum[tid] : 0;
    lds[tid] = v; __syncthreads();
    for (int off = 1; off < 128; off <<= 1) {
        int t = (tid >= off) ? lds[tid - off] : 0;
        __syncthreads();
        lds[tid] += t;
        __syncthreads();
    }
    if (tid < nb) bsum[tid] = lds[tid] - v;
}

// merged: rowptr finalize + dinv + bc + cluster histogram
__global__ void k_nodeinit(int* __restrict__ rowptr, const int* __restrict__ bsum,
                           const int* __restrict__ deg, const int* __restrict__ cluster,
                           const int* __restrict__ inb, float* __restrict__ dinv,
                           int* __restrict__ bc, int* __restrict__ cdeg, int n) {
    int i = blockIdx.x * 256 + threadIdx.x;
    if (i >= n) return;
    rowptr[i] += bsum[i >> 10];
    dinv[i] = rsqrtf((float)deg[i] + 1.0f);
    int c = cluster[i] + inb[i] * NCLUST;
    bc[i] = c;
    atomicAdd(&cdeg[c], 1);
}

__global__ void k_fill(const int* __restrict__ src, const int* __restrict__ dst,
                       const float* __restrict__ dinv, const int* __restrict__ rowptr,
                       int* __restrict__ fill, int* __restrict__ csr_src,
                       float* __restrict__ csr_w, int E) {
    int e = blockIdx.x * 256 + threadIdx.x;
    if (e >= E) return;
    int d = dst[e];
    int pos = rowptr[d] + atomicAdd(&fill[d], 1);
    int s = src[e];
    csr_src[pos] = s;
    csr_w[pos] = dinv[s];
}

__global__ void k_cfill(const int* __restrict__ bc, const int* __restrict__ crowptr,
                        int* __restrict__ cfill, int* __restrict__ cnodes, int n) {
    int i = blockIdx.x * 256 + threadIdx.x;
    if (i >= n) return;
    int c = bc[i];
    int pos = crowptr[c] + atomicAdd(&cfill[c], 1);
    cnodes[pos] = i;
}

// ------ GCN propagation, node-per-wave, edge-split, f32 in / f32 out ------
template <int F>
__global__ __launch_bounds__(256) void k_prop4s(
        const float* __restrict__ h, const float* __restrict__ dinv,
        const int* __restrict__ rowptr, const int* __restrict__ deg,
        const int* __restrict__ csr_src, const float* __restrict__ csr_w,
        const float* __restrict__ bias, float* __restrict__ out,
        int n, int flags) {
    constexpr int FS = F / 4;
    constexpr int ES = 64 / FS;
    const int node = (blockIdx.x * 256 + threadIdx.x) >> 6;
    if (node >= n) return;
    const int l = threadIdx.x & 63;
    const int fs = l & (FS - 1);
    const int ep = l / FS;
    const int fi = fs * 4;
    const int start = rowptr[node];
    const int cnt = deg[node];
    float ax = 0.f, ay = 0.f, az = 0.f, aw = 0.f;
    for (int j = ep; j < cnt; j += ES) {
        int s = csr_src[start + j];
        float w = csr_w[start + j];
        const float4 v = *reinterpret_cast<const float4*>(&h[(size_t)s * F + fi]);
        ax += w * v.x; ay += w * v.y; az += w * v.z; aw += w * v.w;
    }
#pragma unroll
    for (int off = FS; off < 64; off <<= 1) {
        ax += __shfl_xor(ax, off);
        ay += __shfl_xor(ay, off);
        az += __shfl_xor(az, off);
        aw += __shfl_xor(aw, off);
    }
    if (ep == 0) {
        float di = dinv[node];
        const float4 sv = *reinterpret_cast<const float4*>(&h[(size_t)node * F + fi]);
        float4 o;
        o.x = di * ax + di * di * sv.x;
        o.y = di * ay + di * di * sv.y;
        o.z = di * az + di * di * sv.z;
        o.w = di * aw + di * di * sv.w;
        if (flags) {
            const float4 b = *reinterpret_cast<const float4*>(&bias[fi]);
            o.x = elu1(o.x + b.x); o.y = elu1(o.y + b.y);
            o.z = elu1(o.z + b.z); o.w = elu1(o.w + b.w);
        }
        *reinterpret_cast<float4*>(&out[(size_t)node * F + fi]) = o;
    }
}

// ------ GCN propagation, bf16 input; OB=0 f32 out, OB=1 bf16 out ------
template <int F, int OB>
__global__ __launch_bounds__(256) void k_prop4sb(
        const unsigned short* __restrict__ hbf, const float* __restrict__ dinv,
        const int* __restrict__ rowptr, const int* __restrict__ deg,
        const int* __restrict__ csr_src, const float* __restrict__ csr_w,
        const float* __restrict__ bias, float* __restrict__ outf,
        unsigned short* __restrict__ outb, int n, int flags) {
    constexpr int FS = F / 4;
    constexpr int ES = 64 / FS;
    const int node = (blockIdx.x * 256 + threadIdx.x) >> 6;
    if (node >= n) return;
    const int l = threadIdx.x & 63;
    const int fs = l & (FS - 1);
    const int ep = l / FS;
    const int fi = fs * 4;
    const int start = rowptr[node];
    const int cnt = deg[node];
    float ax = 0.f, ay = 0.f, az = 0.f, aw = 0.f;
    for (int j = ep; j < cnt; j += ES) {
        int s = csr_src[start + j];
        float w = csr_w[start + j];
        const ushort4 v = *reinterpret_cast<const ushort4*>(&hbf[(size_t)s * F + fi]);
        ax += w * bf2f(v.x); ay += w * bf2f(v.y);
        az += w * bf2f(v.z); aw += w * bf2f(v.w);
    }
#pragma unroll
    for (int off = FS; off < 64; off <<= 1) {
        ax += __shfl_xor(ax, off);
        ay += __shfl_xor(ay, off);
        az += __shfl_xor(az, off);
        aw += __shfl_xor(aw, off);
    }
    if (ep == 0) {
        float di = dinv[node];
        const ushort4 sv = *reinterpret_cast<const ushort4*>(&hbf[(size_t)node * F + fi]);
        float4 o;
        o.x = di * ax + di * di * bf2f(sv.x);
        o.y = di * ay + di * di * bf2f(sv.y);
        o.z = di * az + di * di * bf2f(sv.z);
        o.w = di * aw + di * di * bf2f(sv.w);
        if (flags) {
            const float4 b = *reinterpret_cast<const float4*>(&bias[fi]);
            o.x = elu1(o.x + b.x); o.y = elu1(o.y + b.y);
            o.z = elu1(o.z + b.z); o.w = elu1(o.w + b.w);
        }
        if constexpr (OB) {
            ushort4 ob;
            ob.x = (unsigned short)f2bf(o.x); ob.y = (unsigned short)f2bf(o.y);
            ob.z = (unsigned short)f2bf(o.z); ob.w = (unsigned short)f2bf(o.w);
            *reinterpret_cast<ushort4*>(&outb[(size_t)node * F + fi]) = ob;
        } else {
            *reinterpret_cast<float4*>(&outf[(size_t)node * F + fi]) = o;
        }
    }
}

__global__ void k_prop3(const float* __restrict__ h, const float* __restrict__ dinv,
                        const int* __restrict__ rowptr, const int* __restrict__ deg,
                        const int* __restrict__ csr_src, const float* __restrict__ csr_w,
                        const float* __restrict__ bias, float* __restrict__ out,
                        int n, int flags) {
    int node = blockIdx.x * 256 + threadIdx.x;
    if (node >= n) return;
    int start = rowptr[node], cnt = deg[node];
    float a0 = 0.f, a1 = 0.f, a2 = 0.f;
    for (int j = 0; j < cnt; j++) {
        int s = csr_src[start + j];
        float w = csr_w[start + j];
        a0 += w * h[(size_t)s * 3 + 0];
        a1 += w * h[(size_t)s * 3 + 1];
        a2 += w * h[(size_t)s * 3 + 2];
    }
    float di = dinv[node];
    float o0 = di * a0 + di * di * h[(size_t)node * 3 + 0];
    float o1 = di * a1 + di * di * h[(size_t)node * 3 + 1];
    float o2 = di * a2 + di * di * h[(size_t)node * 3 + 2];
    if (flags) {
        o0 = elu1(o0 + bias[0]); o1 = elu1(o1 + bias[1]); o2 = elu1(o2 + bias[2]);
    }
    out[(size_t)node * 3 + 0] = o0;
    out[(size_t)node * 3 + 1] = o1;
    out[(size_t)node * 3 + 2] = o2;
}

// ---- W pre-pack: shared body ----
__device__ __forceinline__ void wpack_body(const float* W, const float* scale,
                                           unsigned* Phi, unsigned* Plo,
                                           int K, int BN, int t) {
    int NT = BN / 16;
    int lane = t & 63;
    int rest = t >> 6;
    int ct = rest % NT;
    int s = rest / NT;
    int col = ct * 16 + (lane & 15);
    int g = lane >> 4;
    int k0 = s * 32;
    float e[8];
#pragma unroll
    for (int j = 0; j < 4; j++) {
        int ka = k0 + 4 * g + j;
        int kb = k0 + 16 + 4 * g + j;
        float sa = scale ? scale[ka] : 1.f;
        float sb = scale ? scale[kb] : 1.f;
        e[j]     = W[(size_t)ka * BN + col] * sa;
        e[4 + j] = W[(size_t)kb * BN + col] * sb;
    }
#pragma unroll
    for (int j = 0; j < 4; j++) {
        unsigned h0 = f2bf(e[2 * j]), h1 = f2bf(e[2 * j + 1]);
        Phi[(size_t)t * 4 + j] = h0 | (h1 << 16);
        unsigned l0 = f2bf(e[2 * j] - bf2f(h0));
        unsigned l1 = f2bf(e[2 * j + 1] - bf2f(h1));
        Plo[(size_t)t * 4 + j] = l0 | (l1 << 16);
    }
}

struct PackDesc { const float* W; unsigned* Ph; unsigned* Pl; int K, BN, tbase; };
struct PackArgs { PackDesc d[6]; int tot; };

__global__ void k_wpack_all(PackArgs a) {
    int t = blockIdx.x * 256 + threadIdx.x;
    if (t >= a.tot) return;
    int i = 0;
#pragma unroll
    for (int j = 1; j < 6; j++) if (t >= a.d[j].tbase) i = j;
    wpack_body(a.d[i].W, nullptr, a.d[i].Ph, a.d[i].Pl, a.d[i].K, a.d[i].BN,
               t - a.d[i].tbase);
}

__global__ void k_wpack(const float* __restrict__ W, const float* __restrict__ scale,
                        unsigned* __restrict__ Phi, unsigned* __restrict__ Plo,
                        int K, int BN) {
    int t = blockIdx.x * 256 + threadIdx.x;
    int total = (K / 32) * (BN / 16) * 64;
    if (t >= total) return;
    wpack_body(W, scale, Phi, Plo, K, BN, t);
}

// corr[c] += partial rank-1 instance-norm correction
__global__ void k_corr(const float* __restrict__ W, const float* __restrict__ mu,
                       const float* __restrict__ rstd, float* __restrict__ corr,
                       int M) {
    int c = threadIdx.x;
    if (c >= M) return;
    int k0 = blockIdx.x * 16;
    float s = 0.f;
    for (int k = k0; k < k0 + 16; k++) s += mu[k] * rstd[k] * W[(size_t)k * M + c];
    atomicAdd(&corr[c], s);
}

// ---- split-bf16 MFMA GEMM, 2-stage software pipeline ----
template <int BN, bool ABF>
__global__ __launch_bounds__(256) void k_gmfma(
        const float* __restrict__ A, const unsigned short* __restrict__ Abf,
        const unsigned* __restrict__ Phi, const unsigned* __restrict__ Plo,
        const float* __restrict__ bias, const float* __restrict__ sub,
        const float* __restrict__ add, const int* __restrict__ addidx,
        float* __restrict__ C, unsigned short* __restrict__ Cbf,
        int N, int K, int flags) {
    constexpr int NT = BN / 16;
    constexpr int WCOL = (BN == 256) ? 4 : (BN == 128 ? 2 : 1);
    constexpr int WROW = 4 / WCOL;
    constexpr int NTW = NT / WCOL;
    constexpr int BR = 32 * WROW;
    const int t = threadIdx.x;
    const int w = t >> 6, l = t & 63;
    const int wr = w / WCOL, wc = w % WCOL;
    const int l15 = l & 15, g = l >> 4;
    const int row0 = blockIdx.x * BR + wr * 32;
    const int ctbase = wc * NTW;
    int ar0 = row0 + l15;      ar0 = ar0 < N ? ar0 : N - 1;
    int ar1 = row0 + 16 + l15; ar1 = ar1 < N ? ar1 : N - 1;
    const float* ap0 = ABF ? nullptr : A + (size_t)ar0 * K;
    const float* ap1 = ABF ? nullptr : A + (size_t)ar1 * K;
    const unsigned short* ab0 = ABF ? Abf + (size_t)ar0 * K : nullptr;
    const unsigned short* ab1 = ABF ? Abf + (size_t)ar1 * K : nullptr;

    f32x4 acc[2][NTW];
#pragma unroll
    for (int f = 0; f < 2; f++)
#pragma unroll
        for (int ct = 0; ct < NTW; ct++) acc[f][ct] = (f32x4){0.f, 0.f, 0.f, 0.f};

    auto loadW = [&](int s, U8* wh, U8* wl) {
        const unsigned* pb = Phi + ((size_t)(s * NT + ctbase) * 64 + l) * 4;
        const unsigned* pl = Plo + ((size_t)(s * NT + ctbase) * 64 + l) * 4;
#pragma unroll
        for (int ct = 0; ct < NTW; ct++) {
            wh[ct] = *reinterpret_cast<const U8*>(pb + (size_t)ct * 256);
            wl[ct] = *reinterpret_cast<const U8*>(pl + (size_t)ct * 256);
        }
    };
    auto loadA = [&](int s, U8* ahi, U8* alo) {
        const int k0 = s * 32;
        if constexpr (ABF) {
#pragma unroll
            for (int f = 0; f < 2; f++) {
                const unsigned short* ab = f ? ab1 : ab0;
                const uint2 hA = *reinterpret_cast<const uint2*>(ab + k0 + 4 * g);
                const uint2 hB = *reinterpret_cast<const uint2*>(ab + k0 + 16 + 4 * g);
                ahi[f].u[0] = hA.x; ahi[f].u[1] = hA.y;
                ahi[f].u[2] = hB.x; ahi[f].u[3] = hB.y;
            }
        } else {
#pragma unroll
            for (int f = 0; f < 2; f++) {
                const float* ap = f ? ap1 : ap0;
                const float4 a0 = *reinterpret_cast<const float4*>(ap + k0 + 4 * g);
                const float4 a1 = *reinterpret_cast<const float4*>(ap + k0 + 16 + 4 * g);
                float e[8] = {a0.x, a0.y, a0.z, a0.w, a1.x, a1.y, a1.z, a1.w};
#pragma unroll
                for (int j = 0; j < 4; j++) {
                    unsigned h0 = f2bf(e[2 * j]), h1 = f2bf(e[2 * j + 1]);
                    ahi[f].u[j] = h0 | (h1 << 16);
                    unsigned l0 = f2bf(e[2 * j] - bf2f(h0));
                    unsigned l1 = f2bf(e[2 * j + 1] - bf2f(h1));
                    alo[f].u[j] = l0 | (l1 << 16);
                }
            }
        }
    };
    auto domfma = [&](U8* wh, U8* wl, U8* ahi, U8* alo) {
#pragma unroll
        for (int ct = 0; ct < NTW; ct++) {
            acc[0][ct] = __builtin_amdgcn_mfma_f32_16x16x32_bf16(ahi[0].v, wh[ct].v, acc[0][ct], 0, 0, 0);
            acc[0][ct] = __builtin_amdgcn_mfma_f32_16x16x32_bf16(ahi[0].v, wl[ct].v, acc[0][ct], 0, 0, 0);
            acc[1][ct] = __builtin_amdgcn_mfma_f32_16x16x32_bf16(ahi[1].v, wh[ct].v, acc[1][ct], 0, 0, 0);
            acc[1][ct] = __builtin_amdgcn_mfma_f32_16x16x32_bf16(ahi[1].v, wl[ct].v, acc[1][ct], 0, 0, 0);
            if constexpr (!ABF) {
                acc[0][ct] = __builtin_amdgcn_mfma_f32_16x16x32_bf16(alo[0].v, wh[ct].v, acc[0][ct], 0, 0, 0);
                acc[1][ct] = __builtin_amdgcn_mfma_f32_16x16x32_bf16(alo[1].v, wh[ct].v, acc[1][ct], 0, 0, 0);
            }
        }
    };

    U8 whA[NTW], wlA[NTW], ahiA[2], aloA[2];
    U8 whB[NTW], wlB[NTW], ahiB[2], aloB[2];
    const int nk = K / 32;
    loadW(0, whA, wlA);
    loadA(0, ahiA, aloA);
    int s = 0;
    while (true) {
        const bool hasB = (s + 1 < nk);
        if (hasB) { loadW(s + 1, whB, wlB); loadA(s + 1, ahiB, aloB); }
        domfma(whA, wlA, ahiA, aloA);
        if (!hasB) break;
        const bool hasA2 = (s + 2 < nk);
        if (hasA2) { loadW(s + 2, whA, wlA); loadA(s + 2, ahiA, aloA); }
        domfma(whB, wlB, ahiB, aloB);
        if (!hasA2) break;
        s += 2;
    }
    __syncthreads();   // all A reads done before any store (in-place safe)
#pragma unroll
    for (int f = 0; f < 2; f++) {
#pragma unroll
        for (int r = 0; r < 4; r++) {
            int row = row0 + 16 * f + 4 * g + r;
            if (row >= N) continue;
            int gi = (add != nullptr) ? addidx[row] : 0;
#pragma unroll
            for (int ct = 0; ct < NTW; ct++) {
                int col = (ctbase + ct) * 16 + l15;
                float o = acc[f][ct][r];
                if (add != nullptr) o += add[(size_t)gi * BN + col];
                if (sub != nullptr) o -= sub[col];
                if (flags) o = elu1(o + bias[col]);
                if (C != nullptr) C[(size_t)row * BN + col] = o;
                if (Cbf != nullptr) Cbf[(size_t)row * BN + col] = (unsigned short)f2bf(o);
            }
        }
    }
}

// ---------------- simple fc (small shapes) ----------------
template <int M, int RPT>
__global__ __launch_bounds__(256) void k_fc(
        const float* __restrict__ A, const float* __restrict__ W,
        const float* __restrict__ bias, const float* __restrict__ add,
        const int* __restrict__ addidx, float* __restrict__ C,
        int N, int K, int flags) {
    constexpr int TX = M / 4;
    constexpr int TY = 256 / TX;
    constexpr int RB = TY * RPT;
    int tx = threadIdx.x % TX;
    int ty = threadIdx.x / TX;
    int row0 = blockIdx.x * RB + ty * RPT;
    float4 acc[RPT];
#pragma unroll
    for (int r = 0; r < RPT; r++) acc[r] = make_float4(0.f, 0.f, 0.f, 0.f);
    for (int k = 0; k < K; k++) {
        float4 w = *reinterpret_cast<const float4*>(&W[(size_t)k * M + tx * 4]);
#pragma unroll
        for (int r = 0; r < RPT; r++) {
            int row = row0 + r;
            row = row < N ? row : N - 1;
            float a = A[(size_t)row * K + k];
            acc[r].x += a * w.x; acc[r].y += a * w.y;
            acc[r].z += a * w.z; acc[r].w += a * w.w;
        }
    }
    if (add != nullptr) {
#pragma unroll
        for (int r = 0; r < RPT; r++) {
            int row = row0 + r;
            if (row < N) {
                int g = addidx[row];
                const float4 v = *reinterpret_cast<const float4*>(&add[(size_t)g * M + tx * 4]);
                acc[r].x += v.x; acc[r].y += v.y; acc[r].z += v.z; acc[r].w += v.w;
            }
        }
    }
    __syncthreads();
    float4 b = make_float4(0.f, 0.f, 0.f, 0.f);
    if (flags) b = *reinterpret_cast<const float4*>(&bias[tx * 4]);
#pragma unroll
    for (int r = 0; r < RPT; r++) {
        int row = row0 + r;
        if (row >= N) break;
        float4 o = acc[r];
        o.x += b.x; o.y += b.y; o.z += b.z; o.w += b.w;
        if (flags) { o.x = elu1(o.x); o.y = elu1(o.y); o.z = elu1(o.z); o.w = elu1(o.w); }
        *reinterpret_cast<float4*>(&C[(size_t)row * M + tx * 4]) = o;
    }
}

__global__ void k_fc3(const float* __restrict__ A, const float* __restrict__ W,
                      const float* __restrict__ b, float* __restrict__ C,
                      int n, int K, int flags) {
    int r = blockIdx.x * 256 + threadIdx.x;
    if (r >= n) return;
    float a0 = 0.f, a1 = 0.f, a2 = 0.f;
    for (int k = 0; k < K; k++) {
        float a = A[(size_t)r * K + k];
        a0 += a * W[k * 3 + 0]; a1 += a * W[k * 3 + 1]; a2 += a * W[k * 3 + 2];
    }
    if (flags) {
        a0 = elu1(a0 + b[0]); a1 = elu1(a1 + b[1]); a2 = elu1(a2 + b[2]);
    }
    C[(size_t)r * 3 + 0] = a0;
    C[(size_t)r * 3 + 1] = a1;
    C[(size_t)r * 3 + 2] = a2;
}

// ---------------- instance norm stats (bf16 input) ----------------
__global__ void k_instats(const unsigned short* __restrict__ h, float* __restrict__ sum,
                          float* __restrict__ sumsq, int n) {
    int c = threadIdx.x;
    int r0 = blockIdx.x * 128;
    int r1 = r0 + 128 < n ? r0 + 128 : n;
    float s = 0.f, q = 0.f;
    for (int r = r0; r < r1; r++) {
        float v = bf2f(h[(size_t)r * 256 + c]);
        s += v; q += v * v;
    }
    atomicAdd(&sum[c], s);
    atomicAdd(&sumsq[c], q);
}

__global__ void k_infinal(const float* __restrict__ sum, const float* __restrict__ sumsq,
                          float* __restrict__ mu, float* __restrict__ rstd, int n) {
    int c = threadIdx.x;
    float m = sum[c] / (float)n;
    float var = sumsq[c] / (float)n - m * m;
    mu[c] = m;
    rstd[c] = rsqrtf(var + 1e-5f);
}

// ---------------- cluster pooling (bf16 input, normalize in epilogue) -------
__global__ __launch_bounds__(256) void k_poolavg(
        const unsigned short* __restrict__ xh, const int* __restrict__ crowptr,
        const int* __restrict__ cdeg, const int* __restrict__ cnodes,
        const float* __restrict__ mu, const float* __restrict__ rstd,
        float* __restrict__ px) {
    int cl = blockIdx.x;
    int c  = threadIdx.x;
    int start = crowptr[cl];
    int cnt = cdeg[cl];
    float acc = 0.f;
    for (int j = 0; j < cnt; j++) {
        int node = cnodes[start + j];
        acc += bf2f(xh[(size_t)node * 256 + c]);
    }
    float res = acc / fmaxf((float)cnt, 1.0f);
    res = (cnt > 0) ? (res - mu[c]) * rstd[c] : 0.f;
    px[(size_t)cl * 256 + c] = res;
}

__global__ void k_pooledges(const int* __restrict__ src, const int* __restrict__ dst,
                            const int* __restrict__ bc, unsigned char* __restrict__ bmT, int E) {
    int e = blockIdx.x * 256 + threadIdx.x;
    if (e >= E) return;
    int ps = bc[src[e]];
    int pd = bc[dst[e]];
    bmT[(size_t)pd * NCLUST + ps] = 1;
}

__global__ __launch_bounds__(256) void k_pooldeg(
        const unsigned char* __restrict__ bmT, float* __restrict__ dinvp) {
    int d = blockIdx.x;
    int t = threadIdx.x;
    const unsigned int v = reinterpret_cast<const unsigned int*>(bmT + (size_t)d * NCLUST)[t];
    int s = (v & 0xff) + ((v >> 8) & 0xff) + ((v >> 16) & 0xff) + ((v >> 24) & 0xff);
    if (t == (d >> 2)) s -= (v >> ((d & 3) * 8)) & 0xff;
    __shared__ int red[256];
    red[t] = s; __syncthreads();
    for (int o = 128; o > 0; o >>= 1) {
        if (t < o) red[t] += red[t + o];
        __syncthreads();
    }
    if (t == 0) dinvp[d] = rsqrtf((float)red[0] + 1.0f);
}

template <int F>
__global__ __launch_bounds__(1024) void k_proppool2(
        const float* __restrict__ h, const float* __restrict__ dinvp,
        const unsigned char* __restrict__ bmT, const float* __restrict__ bias,
        float* __restrict__ out) {
    constexpr int SG = 1024 / F;
    const int d = blockIdx.x;
    const int t = threadIdx.x;
    const int f = t & (F - 1);
    const int sg = t / F;
    const unsigned char* bmrow = bmT + (size_t)d * NCLUST;
    float acc = 0.f;
#pragma unroll 4
    for (int s = sg; s < NCLUST; s += SG) {
        float m = (s != d) ? (float)bmrow[s] : 0.f;
        acc += m * dinvp[s] * h[(size_t)s * F + f];
    }
    __shared__ float red[1024];
    red[t] = acc; __syncthreads();
#pragma unroll
    for (int o = SG / 2; o > 0; o >>= 1) {
        if (sg < o) red[t] += red[t + o * F];
        __syncthreads();
    }
    if (sg == 0) {
        float di = dinvp[d];
        float r = di * red[f] + di * di * h[(size_t)d * F + f] + bias[f];
        out[(size_t)d * F + f] = elu1(r);
    }
}

// ---------------------------------------------------------------------------
extern "C" void kernel_launch(void* const* d_in, const int* in_sizes, int n_in,
                              void* d_out, int out_size, void* d_ws, size_t ws_size,
                              hipStream_t stream) {
    const float* x       = (const float*)d_in[0];
    const int*   adj     = (const int*)d_in[1];
    const int*   inb     = (const int*)d_in[3];
    const int*   cluster = (const int*)d_in[4];
    const float* WG1  = (const float*)d_in[5];   const float* bG1  = (const float*)d_in[6];
    const float* WfG1 = (const float*)d_in[7];   const float* bfG1 = (const float*)d_in[8];
    const float* WG2  = (const float*)d_in[9];   const float* bG2  = (const float*)d_in[10];
    const float* WfG2 = (const float*)d_in[11];  const float* bfG2 = (const float*)d_in[12];
    const float* WL1  = (const float*)d_in[13];  const float* bL1  = (const float*)d_in[14];
    const float* WfL1 = (const float*)d_in[15];  const float* bfL1 = (const float*)d_in[16];
    const float* WL2  = (const float*)d_in[17];  const float* bL2  = (const float*)d_in[18];
    const float* WfL2 = (const float*)d_in[19];  const float* bfL2 = (const float*)d_in[20];
    const float* WO1  = (const float*)d_in[21];  const float* bO1  = (const float*)d_in[22];
    const float* WfO1 = (const float*)d_in[23];  const float* bfO1 = (const float*)d_in[24];
    const float* WO2  = (const float*)d_in[25];  const float* bO2  = (const float*)d_in[26];
    const float* WfO2 = (const float*)d_in[27];  const float* bfO2 = (const float*)d_in[28];
    const float* WO3  = (const float*)d_in[29];  const float* bO3  = (const float*)d_in[30];
    const float* WfO3 = (const float*)d_in[31];  const float* bfO3 = (const float*)d_in[32];
    float* out = (float*)d_out;

    const int n = in_sizes[0] / 3;       // 100000
    const int E = in_sizes[1] / 2;       // 1600000
    const int* src = adj;
    const int* dst = adj + E;

    // ---- workspace carve (~250 MB) ----
    char* ws = (char*)d_ws;
    size_t off = 0;
    auto alloc = [&](size_t bytes) -> void* {
        void* p = ws + off;
        off = (off + bytes + 255) & ~(size_t)255;
        return p;
    };
    int*   deg     = (int*)alloc((size_t)n * 4);     // zero span 1 start
    int*   fill    = (int*)alloc((size_t)n * 4);
    int*   cdeg    = (int*)alloc(NCLUST * 4);
    int*   cfill   = (int*)alloc(NCLUST * 4);
    int*   rowptr  = (int*)alloc((size_t)n * 4);     // zero span 1 end (exclusive)
    int*   crowptr = (int*)alloc(NCLUST * 4);
    int*   cnodes  = (int*)alloc((size_t)n * 4);
    int*   bcarr   = (int*)alloc((size_t)n * 4);
    float* dinv    = (float*)alloc((size_t)n * 4);
    int*   bsum    = (int*)alloc(512);
    int*   csr_src = (int*)alloc((size_t)E * 4);
    float* csr_w   = (float*)alloc((size_t)E * 4);
    float* X       = (float*)alloc((size_t)n * 256 * 4);
    unsigned short* Xh = (unsigned short*)alloc((size_t)n * 256 * 2);  // bf16 act
    float* B       = (float*)alloc((size_t)n * 128 * 4);
    unsigned short* Bh = (unsigned short*)alloc((size_t)n * 128 * 2);  // bf16 h2/t1/t2
    float* insum   = (float*)alloc(256 * 4);         // zero span 2 start
    float* insumsq = (float*)alloc(256 * 4);
    float* px      = (float*)alloc((size_t)NCLUST * 256 * 4);
    unsigned char* bmT = (unsigned char*)alloc((size_t)NCLUST * NCLUST);
    float* corr    = (float*)alloc(128 * 4);
    float* mu      = (float*)alloc(256 * 4);         // zero span 2 end (exclusive)
    float* rstd    = (float*)alloc(256 * 4);
    float* dinvp   = (float*)alloc(NCLUST * 4);
    float* lA      = (float*)alloc((size_t)NCLUST * 128 * 4);
    float* lB      = (float*)alloc((size_t)NCLUST * 128 * 4);
    unsigned* pfG1h = (unsigned*)alloc(2048 * 4);   unsigned* pfG1l = (unsigned*)alloc(2048 * 4);
    unsigned* pG2h  = (unsigned*)alloc(8192 * 4);   unsigned* pG2l  = (unsigned*)alloc(8192 * 4);
    unsigned* pfG2h = (unsigned*)alloc(32768 * 4);  unsigned* pfG2l = (unsigned*)alloc(32768 * 4);
    unsigned* pO1h  = (unsigned*)alloc(16384 * 4);  unsigned* pO1l  = (unsigned*)alloc(16384 * 4);
    unsigned* pfO1h = (unsigned*)alloc(8192 * 4);   unsigned* pfO1l = (unsigned*)alloc(8192 * 4);
    unsigned* pO2h  = (unsigned*)alloc(2048 * 4);   unsigned* pO2l  = (unsigned*)alloc(2048 * 4);
    unsigned* pfO2h = (unsigned*)alloc(512 * 4);    unsigned* pfO2l = (unsigned*)alloc(512 * 4);
    (void)ws_size; (void)n_in; (void)out_size;

    float* B0 = B;
    float* B1 = B + (size_t)n * 64;

    auto cdiv = [](int a, int b) { return (a + b - 1) / b; };
    const int EB = cdiv(E, 256);
    const int GB32 = cdiv(n, 32);        // gmfma grid, BN=256
    const int GB64 = cdiv(n, 64);        // gmfma grid, BN=128
    const int GB128 = cdiv(n, 128);      // gmfma grid, BN<=64
    const int PB = cdiv(n, 4);           // prop grid (node per wave)

    // ---- zero scratch (single launch) ----
    int nz1 = (int)(((char*)rowptr - (char*)deg) / 16);
    int nz2 = (int)(((char*)mu - (char*)insum) / 16);
    k_zero2<<<cdiv(nz1 + nz2, 256), 256, 0, stream>>>((int4*)deg, nz1, (int4*)insum, nz2);

    // ---- pack all static weights in ONE launch ----
    PackArgs pa;
    pa.d[0] = {WfG1, pfG1h, pfG1l, 64, 64, 0};          // 512 threads
    pa.d[1] = {WG2,  pG2h,  pG2l,  64, 256, 512};       // 2048
    pa.d[2] = {WfG2, pfG2h, pfG2l, 256, 256, 2560};     // 8192
    pa.d[3] = {WfO1, pfO1h, pfO1l, 128, 128, 10752};    // 2048
    pa.d[4] = {WO2,  pO2h,  pO2l,  128, 32, 12800};     // 512
    pa.d[5] = {WfO2, pfO2h, pfO2l, 32, 32, 13312};      // 128
    pa.tot = 13440;
    k_wpack_all<<<cdiv(13440, 256), 256, 0, stream>>>(pa);

    // ---- CSR build (edges + clusters, merged node pass) ----
    k_hist<<<EB, 256, 0, stream>>>(dst, deg, E);
    int nb = cdiv(n, 1024);
    k_scan_block<<<nb, 256, 0, stream>>>(deg, rowptr, bsum, n);
    k_scan_tops<<<1, 128, 0, stream>>>(bsum, nb);
    k_nodeinit<<<cdiv(n, 256), 256, 0, stream>>>(rowptr, bsum, deg, cluster, inb,
                                                 dinv, bcarr, cdeg, n);
    k_fill<<<EB, 256, 0, stream>>>(src, dst, dinv, rowptr, fill, csr_src, csr_w, E);
    k_scan_block<<<1, 256, 0, stream>>>(cdeg, crowptr, bsum, NCLUST);
    k_cfill<<<cdiv(n, 256), 256, 0, stream>>>(bcarr, crowptr, cfill, cnodes, n);

    // ---- global GCN stack ----
    k_prop3<<<cdiv(n, 256), 256, 0, stream>>>(x, dinv, rowptr, deg, csr_src, csr_w,
                                              nullptr, B0, n, 0);
    k_fc<64, 2><<<cdiv(n, 32), 256, 0, stream>>>(B0, WG1, bG1, nullptr, nullptr, B1, n, 3, 1);
    // h2 = elu(h1 @ WfG1 + bfG1)  -> bf16 (Bh, n x 64)
    k_gmfma<64, false><<<GB128, 256, 0, stream>>>(B1, nullptr, pfG1h, pfG1l, bfG1,
                                                  nullptr, nullptr, nullptr, nullptr, Bh,
                                                  n, 64, 1);
    // p64 = S h2  (bf16 gather -> f32 B0)
    k_prop4sb<64, 0><<<PB, 256, 0, stream>>>(Bh, dinv, rowptr, deg, csr_src, csr_w,
                                             nullptr, B0, nullptr, n, 0);
    // h3 = elu(p64 @ WG2 + bG2)  -> bf16 ONLY (Xh)
    k_gmfma<256, false><<<GB32, 256, 0, stream>>>(B0, nullptr, pG2h, pG2l, bG2,
                                                  nullptr, nullptr, nullptr, nullptr, Xh,
                                                  n, 64, 1);
    // h4 = elu(h3 @ WfG2 + bfG2)  (bf16-A, Xh in-place, bf16 ONLY out)
    k_gmfma<256, true><<<GB32, 256, 0, stream>>>(nullptr, Xh, pfG2h, pfG2l, bfG2,
                                                 nullptr, nullptr, nullptr, nullptr, Xh,
                                                 n, 256, 1);

    // ---- instance norm stats from bf16 Xh ----
    k_instats<<<cdiv(n, 128), 256, 0, stream>>>(Xh, insum, insumsq, n);
    k_infinal<<<1, 256, 0, stream>>>(insum, insumsq, mu, rstd, n);
    k_wpack<<<cdiv(4096, 256), 256, 0, stream>>>(WO1, rstd, pO1h, pO1l, 256, 128);
    k_corr<<<16, 128, 0, stream>>>(WO1, mu, rstd, corr, 128);

    // ---- cluster pooling (bf16 Xh + affine fixup in epilogue) ----
    k_poolavg<<<NCLUST, 256, 0, stream>>>(Xh, crowptr, cdeg, cnodes, mu, rstd, px);
    k_pooledges<<<EB, 256, 0, stream>>>(src, dst, bcarr, bmT, E);
    k_pooldeg<<<NCLUST, 256, 0, stream>>>(bmT, dinvp);

    // ---- local (pooled) GCN stack ----
    k_fc<128, 2><<<cdiv(NCLUST, 16), 256, 0, stream>>>(px, WL1, nullptr, nullptr, nullptr,
                                                       lA, NCLUST, 256, 0);
    k_proppool2<128><<<NCLUST, 1024, 0, stream>>>(lA, dinvp, bmT, bL1, lB);
    k_fc<128, 2><<<cdiv(NCLUST, 16), 256, 0, stream>>>(lB, WfL1, bfL1, nullptr, nullptr,
                                                       lA, NCLUST, 128, 1);
    k_fc<64, 2><<<cdiv(NCLUST, 32), 256, 0, stream>>>(lA, WL2, nullptr, nullptr, nullptr,
                                                      lB, NCLUST, 128, 0);
    k_proppool2<64><<<NCLUST, 1024, 0, stream>>>(lB, dinvp, bmT, bL2, lA);
    k_fc<64, 2><<<cdiv(NCLUST, 32), 256, 0, stream>>>(lA, WfL2, bfL2, nullptr, nullptr,
                                                      lB, NCLUST, 64, 1);
    k_fc<128, 2><<<cdiv(NCLUST, 16), 256, 0, stream>>>(lB, WO1 + (size_t)256 * 128, nullptr,
                                                       nullptr, nullptr, lA, NCLUST, 64, 0);

    // ---- output GCN stack ----
    // t1 = Xh @ (rstd*WO1) - corr + compO[bc]  -> bf16 (Bh)
    k_gmfma<128, true><<<GB64, 256, 0, stream>>>(nullptr, Xh, pO1h, pO1l, nullptr,
                                                 corr, lA, bcarr, nullptr, Bh,
                                                 n, 256, 0);
    // o1 = elu(S t1 + bO1)  -> bf16 (Xh, stride 128)
    k_prop4sb<128, 1><<<PB, 256, 0, stream>>>(Bh, dinv, rowptr, deg, csr_src, csr_w,
                                              bO1, nullptr, Xh, n, 1);
    // o2 = elu(o1 @ WfO1 + bfO1)  (bf16-A, Xh in-place)
    k_gmfma<128, true><<<GB64, 256, 0, stream>>>(nullptr, Xh, pfO1h, pfO1l, bfO1,
                                                 nullptr, nullptr, nullptr, nullptr, Xh,
                                                 n, 128, 1);
    // t2 = o2 @ WO2  -> bf16 (Bh, N x 32)
    k_gmfma<32, true><<<GB128, 256, 0, stream>>>(nullptr, Xh, pO2h, pO2l, nullptr,
                                                 nullptr, nullptr, nullptr, nullptr, Bh,
                                                 n, 128, 0);
    // o3 = elu(S t2 + bO2)  -> bf16 (Xh, stride 32)
    k_prop4sb<32, 1><<<PB, 256, 0, stream>>>(Bh, dinv, rowptr, deg, csr_src, csr_w,
                                             bO2, nullptr, Xh, n, 1);
    // o4 = elu(o3 @ WfO2 + bfO2)  (bf16-A, f32 out X)
    k_gmfma<32, true><<<GB128, 256, 0, stream>>>(nullptr, Xh, pfO2h, pfO2l, bfO2,
                                                 nullptr, nullptr, nullptr, X, nullptr,
                                                 n, 32, 1);
    k_fc3<<<cdiv(n, 256), 256, 0, stream>>>(X, WO3, nullptr, B, n, 32, 0);
    k_prop3<<<cdiv(n, 256), 256, 0, stream>>>(B, dinv, rowptr, deg, csr_src, csr_w,
                                              bO3, X, n, 1);
    k_fc3<<<cdiv(n, 256), 256, 0, stream>>>(X, WfO3, bfO3, out, n, 3, 1);
}